// Round 1
// baseline (1968.550 us; speedup 1.0000x reference)
//
#include <hip/hip_runtime.h>

#define PP 8192
#define DD 512
#define NSPLIT 2
#define KEYS_PER_SPLIT (PP / NSPLIT)
#define NJT (KEYS_PER_SPLIT / 64)

typedef short bf16x8 __attribute__((ext_vector_type(8)));
typedef float f32x4 __attribute__((ext_vector_type(4)));
typedef unsigned short u16;
typedef unsigned int u32;

__device__ __forceinline__ u16 f2bf(float x) {
  u32 u = __float_as_uint(x);
  u += 0x7fffu + ((u >> 16) & 1u);   // RNE
  return (u16)(u >> 16);
}
__device__ __forceinline__ float bf2f(u16 h) {
  return __uint_as_float(((u32)h) << 16);
}
__device__ __forceinline__ f32x4 mfma_bf16(bf16x8 a, bf16x8 b, f32x4 c) {
  return __builtin_amdgcn_mfma_f32_16x16x32_bf16(a, b, c, 0, 0, 0);
}
__device__ __forceinline__ void gload_lds16(const u16* g, u16* l) {
  __builtin_amdgcn_global_load_lds(
      (const __attribute__((address_space(1))) void*)g,
      (__attribute__((address_space(3))) void*)l, 16, 0, 0);
}

// ---- prep: transpose Wq,Wk to bf16; Wv to bf16 ------------------------------
__global__ void prep_wt_kernel(const float* __restrict__ Wq, const float* __restrict__ Wk,
                               const float* __restrict__ Wv, u16* __restrict__ WqT,
                               u16* __restrict__ WkT, u16* __restrict__ Wvb) {
  int i = blockIdx.x * 256 + threadIdx.x;   // 1024 blocks x 256 = 512*512
  int a = i >> 9, k = i & 511;
  WqT[(size_t)k * DD + a] = f2bf(Wq[i]);
  WkT[(size_t)k * DD + a] = f2bf(Wk[i]);
  Wvb[i] = f2bf(Wv[i]);
}

// ---- kb[k] = (bq . Wk[:,k]) / sqrt(d)  (column-bias term v_j = F_j . kb) ----
__global__ void kb_kernel(const float* __restrict__ Wk, const float* __restrict__ bq,
                          float* __restrict__ kb) {
  int k = threadIdx.x;  // 512 threads, 1 block
  float s = 0.f;
  for (int a = 0; a < DD; ++a) s += bq[a] * Wk[(size_t)a * DD + k];
  kb[k] = s * 0.04419417382415922f;
}

// ---- prep F: bf16 + per-row (sq-norm, v-bias) from ROUNDED values -----------
__global__ void prep_f_kernel(const float* __restrict__ F, const float* __restrict__ kb,
                              u16* __restrict__ Fb, float2* __restrict__ nv) {
  int wid = threadIdx.x >> 6, lane = threadIdx.x & 63;
  int row = blockIdx.x * 4 + wid;
  const float* src = F + (size_t)row * DD + lane * 8;
  float4 a = *(const float4*)src;
  float4 b = *(const float4*)(src + 4);
  float v[8] = {a.x, a.y, a.z, a.w, b.x, b.y, b.z, b.w};
  const float* kp = kb + lane * 8;
  float4 ka = *(const float4*)kp;
  float4 kc = *(const float4*)(kp + 4);
  float kw[8] = {ka.x, ka.y, ka.z, ka.w, kc.x, kc.y, kc.z, kc.w};
  u16 h[8];
  float s = 0.f, d = 0.f;
#pragma unroll
  for (int j = 0; j < 8; ++j) {
    h[j] = f2bf(v[j]);
    float f = bf2f(h[j]);
    s += f * f;
    d += f * kw[j];
  }
  u32 pk[4];
#pragma unroll
  for (int j = 0; j < 4; ++j) pk[j] = (u32)h[2 * j] | ((u32)h[2 * j + 1] << 16);
  *(uint4*)(Fb + (size_t)row * DD + lane * 8) = make_uint4(pk[0], pk[1], pk[2], pk[3]);
#pragma unroll
  for (int dd = 1; dd < 64; dd <<= 1) { s += __shfl_xor(s, dd); d += __shfl_xor(d, dd); }
  if (lane == 0) nv[row] = make_float2(s, d);
}

// ---- MT[m][k] = (Wq^T Wk)^T[m][k] / sqrt(d) = sum_a WkT[m,a]*WqT[k,a] -------
__global__ __launch_bounds__(256) void mt_kernel(const u16* __restrict__ WkT,
                                                 const u16* __restrict__ WqT,
                                                 u16* __restrict__ MT) {
  int lane = threadIdx.x & 63, wm = threadIdx.x >> 6;
  int l15 = lane & 15, lg = lane >> 4;
  int rowA = blockIdx.x * 64 + wm * 16 + l15;
  int rowC0 = blockIdx.x * 64 + wm * 16 + lg * 4;
  int colbase = blockIdx.y * 64;
  f32x4 z = {0.f, 0.f, 0.f, 0.f};
  f32x4 acc[4] = {z, z, z, z};
#pragma unroll
  for (int kk = 0; kk < 16; ++kk) {
    bf16x8 aF = *(const bf16x8*)(WkT + (size_t)rowA * DD + kk * 32 + lg * 8);
#pragma unroll
    for (int nf = 0; nf < 4; ++nf) {
      bf16x8 bW = *(const bf16x8*)(WqT + (size_t)(colbase + nf * 16 + l15) * DD + kk * 32 + lg * 8);
      acc[nf] = mfma_bf16(aF, bW, acc[nf]);
    }
  }
  const float isd = 0.04419417382415922f;
#pragma unroll
  for (int nf = 0; nf < 4; ++nf) {
    int col = colbase + nf * 16 + l15;
#pragma unroll
    for (int r = 0; r < 4; ++r)
      MT[(size_t)(rowC0 + r) * DD + col] = f2bf(acc[nf][r] * isd);
  }
}

// ---- G = Fb @ MT^T (mat 0) ; V = Fb @ Wv^T + bv -> Vt (mat 1) ---------------
__global__ __launch_bounds__(256) void gv_kernel(
    const u16* __restrict__ Fb, const u16* __restrict__ MT, const u16* __restrict__ Wvb,
    const float* __restrict__ bv, u16* __restrict__ G, u16* __restrict__ Vt) {
  int mat = blockIdx.z;
  const u16* W = (mat == 0) ? MT : Wvb;
  int lane = threadIdx.x & 63, wm = threadIdx.x >> 6;
  int l15 = lane & 15, lg = lane >> 4;
  int rowA = blockIdx.x * 64 + wm * 16 + l15;
  int rowC0 = blockIdx.x * 64 + wm * 16 + lg * 4;
  int colbase = blockIdx.y * 64;
  f32x4 z = {0.f, 0.f, 0.f, 0.f};
  f32x4 acc[4] = {z, z, z, z};
#pragma unroll
  for (int kk = 0; kk < 16; ++kk) {
    bf16x8 aF = *(const bf16x8*)(Fb + (size_t)rowA * DD + kk * 32 + lg * 8);
#pragma unroll
    for (int nf = 0; nf < 4; ++nf) {
      bf16x8 bW = *(const bf16x8*)(W + (size_t)(colbase + nf * 16 + l15) * DD + kk * 32 + lg * 8);
      acc[nf] = mfma_bf16(aF, bW, acc[nf]);
    }
  }
#pragma unroll
  for (int nf = 0; nf < 4; ++nf) {
    int col = colbase + nf * 16 + l15;
    if (mat == 1) {
      float bb = bv[col];
      ushort4 vv = make_ushort4(f2bf(acc[nf][0] + bb), f2bf(acc[nf][1] + bb),
                                f2bf(acc[nf][2] + bb), f2bf(acc[nf][3] + bb));
      *(ushort4*)(Vt + (size_t)col * PP + rowC0) = vv;
    } else {
#pragma unroll
      for (int r = 0; r < 4; ++r)
        G[(size_t)(rowC0 + r) * DD + col] = f2bf(acc[nf][r]);
    }
  }
}

// ---- fused flash attention + dist, split-K over keys ------------------------
// grid (256, 2): blockIdx.x = 32-row tile, blockIdx.y = key half (4096 keys).
// 512 threads = 8 waves (wm 2 x wn 4), BN=64 keys/iter, 64 iters per block.
// Single-buffered key tile (64 KiB LDS total ~70 KiB) + VGPR<=128 -> 2 blocks/CU.
// Partial (unnorm O, m, l) per split; merged by merge_kernel.
__global__ __launch_bounds__(512, 4) void fused_kernel(
    const u16* __restrict__ G, const u16* __restrict__ Fb, const u16* __restrict__ Vt,
    const float2* __restrict__ nv, const float* __restrict__ lamp,
    float* __restrict__ out, float* __restrict__ Opart, float* __restrict__ ml) {
  float* Fout = out;
  float* Dist = out + (size_t)PP * DD;
  const float lam = lamp[0];
  int lane = threadIdx.x & 63, wid = threadIdx.x >> 6;
  int wm = wid >> 2, wn = wid & 3;
  int l15 = lane & 15, lg = lane >> 4;
  int rowA = blockIdx.x * 32 + wm * 16 + l15;
  int rowC0 = blockIdx.x * 32 + wm * 16 + lg * 4;
  int kbase = blockIdx.y * KEYS_PER_SPLIT;

  __shared__ u16 Ftile[64][DD];      // 64 KiB single-buffered key tile
  __shared__ u16 P_lds[32][72];
  __shared__ float redmax[8][16];
  __shared__ float redsum[8][16];

  // resident A-fragments: G (scores) and F (Gram) rows
  bf16x8 gf[16], ff[16];
#pragma unroll
  for (int c = 0; c < 16; ++c) {
    gf[c] = *(const bf16x8*)(G + (size_t)rowA * DD + c * 32 + lg * 8);
    ff[c] = *(const bf16x8*)(Fb + (size_t)rowA * DD + c * 32 + lg * 8);
  }
  float ni[4];
#pragma unroll
  for (int r = 0; r < 4; ++r) ni[r] = nv[rowC0 + r].x;
  float m_run[4], l_run[4];
#pragma unroll
  for (int r = 0; r < 4; ++r) { m_run[r] = -1e30f; l_run[r] = 0.f; }
  f32x4 z = {0.f, 0.f, 0.f, 0.f};
  f32x4 o[8] = {z, z, z, z, z, z, z, z};

  int kl = wn * 16 + l15;      // B-side key_local
  int swz = kl & 7;

  // prologue: stage tile 0
#pragma unroll
  for (int t = 0; t < 8; ++t) {
    int row = wid * 8 + t;
    gload_lds16(Fb + (size_t)(kbase + row) * DD + ((lane ^ (row & 7)) * 8), &Ftile[row][0]);
  }
  __syncthreads();

#pragma unroll 1
  for (int jt = 0; jt < NJT; ++jt) {
    int key0 = kbase + jt * 64;
    // S phase: scores (G.F^T) and Gram (F.F^T) off shared B-frags
    const u16* ft = &Ftile[0][0];
    f32x4 sqk = z, sff = z;
#pragma unroll
    for (int kk = 0; kk < 16; ++kk) {
      bf16x8 bF = *(const bf16x8*)(ft + (size_t)kl * DD + (((kk * 4 + lg) ^ swz) * 8));
      sqk = mfma_bf16(gf[kk], bF, sqk);
      sff = mfma_bf16(ff[kk], bF, sff);
    }
    int colB = key0 + kl;
    float2 nvj = nv[colB];
    float pv[4], tmax[4];
#pragma unroll
    for (int r = 0; r < 4; ++r) {
      float sq = ni[r] + nvj.x - 2.0f * sff[r];
      sq = fmaxf(sq, 0.f);
      float dist = sqrtf(sq);
      Dist[(size_t)(rowC0 + r) * PP + colB] = dist;
      float s = sqk[r] + nvj.y - lam * dist;
      pv[r] = s;
      tmax[r] = s;
    }
#pragma unroll
    for (int d = 1; d < 16; d <<= 1) {
#pragma unroll
      for (int r = 0; r < 4; ++r) tmax[r] = fmaxf(tmax[r], __shfl_xor(tmax[r], d));
    }
    if (l15 == 0) {
#pragma unroll
      for (int r = 0; r < 4; ++r) redmax[wid][lg * 4 + r] = tmax[r];
    }
    __syncthreads();  // b1: redmax visible; all S-reads of Ftile done
    // stage next tile into the (now free) single buffer; drained at b2
    if (jt + 1 < NJT) {
      int nk = kbase + (jt + 1) * 64;
#pragma unroll
      for (int t = 0; t < 8; ++t) {
        int row = wid * 8 + t;
        gload_lds16(Fb + (size_t)(nk + row) * DD + ((lane ^ (row & 7)) * 8), &Ftile[row][0]);
      }
    }
    float mnew[4], alpha[4];
#pragma unroll
    for (int r = 0; r < 4; ++r) {
      float mt = m_run[r];
#pragma unroll
      for (int ow = 0; ow < 4; ++ow) mt = fmaxf(mt, redmax[wm * 4 + ow][lg * 4 + r]);
      mnew[r] = mt;
      alpha[r] = __expf(m_run[r] - mt);
    }
    float tsum[4];
#pragma unroll
    for (int r = 0; r < 4; ++r) { pv[r] = __expf(pv[r] - mnew[r]); tsum[r] = pv[r]; }
#pragma unroll
    for (int d = 1; d < 16; d <<= 1) {
#pragma unroll
      for (int r = 0; r < 4; ++r) tsum[r] += __shfl_xor(tsum[r], d);
    }
#pragma unroll
    for (int r = 0; r < 4; ++r)
      P_lds[wm * 16 + lg * 4 + r][wn * 16 + l15] = f2bf(pv[r]);
    if (l15 == 0) {
#pragma unroll
      for (int r = 0; r < 4; ++r) redsum[wid][lg * 4 + r] = tsum[r];
    }
    __syncthreads();  // b2 (also drains staging loads)
#pragma unroll
    for (int r = 0; r < 4; ++r) {
      float s4 = 0.f;
#pragma unroll
      for (int ow = 0; ow < 4; ++ow) s4 += redsum[wm * 4 + ow][lg * 4 + r];
      l_run[r] = l_run[r] * alpha[r] + s4;
      m_run[r] = mnew[r];
    }
#pragma unroll
    for (int nt = 0; nt < 8; ++nt) {
#pragma unroll
      for (int r = 0; r < 4; ++r) o[nt][r] *= alpha[r];
    }
#pragma unroll
    for (int kc = 0; kc < 2; ++kc) {
      bf16x8 aP = *(const bf16x8*)(&P_lds[wm * 16 + l15][kc * 32 + lg * 8]);
#pragma unroll
      for (int nt = 0; nt < 8; ++nt) {
        int n = wn * 128 + nt * 16 + l15;
        bf16x8 bV = *(const bf16x8*)(Vt + (size_t)n * PP + key0 + kc * 32 + lg * 8);
        o[nt] = mfma_bf16(aP, bV, o[nt]);
      }
    }
  }
  // epilogue: store UNNORMALIZED partial O + per-row (m, l)
  float* Od = (blockIdx.y == 0) ? Fout : Opart;
#pragma unroll
  for (int nt = 0; nt < 8; ++nt) {
#pragma unroll
    for (int r = 0; r < 4; ++r)
      Od[(size_t)(rowC0 + r) * DD + wn * 128 + nt * 16 + l15] = o[nt][r];
  }
  if (wn == 0 && l15 == 0) {
#pragma unroll
    for (int r = 0; r < 4; ++r) {
      ml[(size_t)(blockIdx.y * 2 + 0) * PP + rowC0 + r] = m_run[r];
      ml[(size_t)(blockIdx.y * 2 + 1) * PP + rowC0 + r] = l_run[r];
    }
  }
}

// ---- merge the two key-split partials: out = (O0*w0 + O1*w1)/(l0*w0+l1*w1) --
__global__ __launch_bounds__(256) void merge_kernel(float* __restrict__ out,
                                                    const float* __restrict__ Opart,
                                                    const float* __restrict__ ml) {
  int i = blockIdx.x * 256 + threadIdx.x;   // PP*DD/4 threads, float4 each
  int row = i >> 7;                          // DD/4 = 128 float4 per row
  int c = (i & 127) * 4;
  float m0 = ml[row];
  float l0 = ml[PP + row];
  float m1 = ml[2 * PP + row];
  float l1 = ml[3 * PP + row];
  float m = fmaxf(m0, m1);
  float w0 = __expf(m0 - m), w1 = __expf(m1 - m);
  float inv = 1.0f / (l0 * w0 + l1 * w1);
  w0 *= inv; w1 *= inv;
  float4 a = *(const float4*)(out + (size_t)row * DD + c);
  float4 b = *(const float4*)(Opart + (size_t)row * DD + c);
  a.x = a.x * w0 + b.x * w1;
  a.y = a.y * w0 + b.y * w1;
  a.z = a.z * w0 + b.z * w1;
  a.w = a.w * w0 + b.w * w1;
  *(float4*)(out + (size_t)row * DD + c) = a;
}

extern "C" void kernel_launch(void* const* d_in, const int* in_sizes, int n_in,
                              void* d_out, int out_size, void* d_ws, size_t ws_size,
                              hipStream_t stream) {
  const float* F   = (const float*)d_in[0];
  const float* Wq  = (const float*)d_in[1];
  const float* bq  = (const float*)d_in[2];
  const float* Wk  = (const float*)d_in[3];
  const float* bk  = (const float*)d_in[4];
  const float* Wv  = (const float*)d_in[5];
  const float* bv  = (const float*)d_in[6];
  const float* lam = (const float*)d_in[7];
  float* out = (float*)d_out;
  (void)bk;

  u16* ws  = (u16*)d_ws;
  u16* Fb  = ws;                               // [PP][DD]
  u16* G   = Fb + (size_t)PP * DD;             // [PP][DD]
  u16* Vt  = G + (size_t)PP * DD;              // [DD][PP]
  u16* WqT = Vt + (size_t)PP * DD;             // [DD][DD]
  u16* WkT = WqT + (size_t)DD * DD;
  u16* Wvb = WkT + (size_t)DD * DD;
  u16* MT  = Wvb + (size_t)DD * DD;
  float2* nv = (float2*)(MT + (size_t)DD * DD);  // [PP]
  float* kb  = (float*)(nv + PP);                // [DD]
  float* Opart = (float*)(kb + DD);              // [PP][DD] f32 (split-1 partial)
  float* mlbuf = Opart + (size_t)PP * DD;        // [4][PP]: m0,l0,m1,l1

  prep_wt_kernel<<<1024, 256, 0, stream>>>(Wq, Wk, Wv, WqT, WkT, Wvb);
  kb_kernel<<<1, 512, 0, stream>>>(Wk, bq, kb);
  prep_f_kernel<<<PP / 4, 256, 0, stream>>>(F, kb, Fb, nv);
  mt_kernel<<<dim3(8, 8), 256, 0, stream>>>(WkT, WqT, MT);
  gv_kernel<<<dim3(PP / 64, DD / 64, 2), 256, 0, stream>>>(Fb, MT, Wvb, bv, G, Vt);
  fused_kernel<<<dim3(PP / 32, NSPLIT), 512, 0, stream>>>(G, Fb, Vt, nv, lam, out, Opart, mlbuf);
  merge_kernel<<<PP * DD / 4 / 256, 256, 0, stream>>>(out, Opart, mlbuf);
}

// Round 2
// 946.000 us; speedup vs baseline: 2.0809x; 2.0809x over previous
//
#include <hip/hip_runtime.h>

#define PP 8192
#define DD 512

typedef short bf16x8 __attribute__((ext_vector_type(8)));
typedef float f32x4 __attribute__((ext_vector_type(4)));
typedef unsigned short u16;
typedef unsigned int u32;

__device__ __forceinline__ u16 f2bf(float x) {
  u32 u = __float_as_uint(x);
  u += 0x7fffu + ((u >> 16) & 1u);   // RNE
  return (u16)(u >> 16);
}
__device__ __forceinline__ float bf2f(u16 h) {
  return __uint_as_float(((u32)h) << 16);
}
__device__ __forceinline__ f32x4 mfma_bf16(bf16x8 a, bf16x8 b, f32x4 c) {
  return __builtin_amdgcn_mfma_f32_16x16x32_bf16(a, b, c, 0, 0, 0);
}
__device__ __forceinline__ void gload_lds16(const u16* g, u16* l) {
  __builtin_amdgcn_global_load_lds(
      (const __attribute__((address_space(1))) void*)g,
      (__attribute__((address_space(3))) void*)l, 16, 0, 0);
}

// ---- prep: transpose Wq,Wk to bf16; Wv to bf16 ------------------------------
__global__ void prep_wt_kernel(const float* __restrict__ Wq, const float* __restrict__ Wk,
                               const float* __restrict__ Wv, u16* __restrict__ WqT,
                               u16* __restrict__ WkT, u16* __restrict__ Wvb) {
  int i = blockIdx.x * 256 + threadIdx.x;   // 1024 blocks x 256 = 512*512
  int a = i >> 9, k = i & 511;
  WqT[(size_t)k * DD + a] = f2bf(Wq[i]);
  WkT[(size_t)k * DD + a] = f2bf(Wk[i]);
  Wvb[i] = f2bf(Wv[i]);
}

// ---- kb[k] = (bq . Wk[:,k]) / sqrt(d)  (column-bias term v_j = F_j . kb) ----
__global__ void kb_kernel(const float* __restrict__ Wk, const float* __restrict__ bq,
                          float* __restrict__ kb) {
  int k = threadIdx.x;  // 512 threads, 1 block
  float s = 0.f;
  for (int a = 0; a < DD; ++a) s += bq[a] * Wk[(size_t)a * DD + k];
  kb[k] = s * 0.04419417382415922f;
}

// ---- prep F: bf16 + per-row (sq-norm, v-bias) from ROUNDED values -----------
__global__ void prep_f_kernel(const float* __restrict__ F, const float* __restrict__ kb,
                              u16* __restrict__ Fb, float2* __restrict__ nv) {
  int wid = threadIdx.x >> 6, lane = threadIdx.x & 63;
  int row = blockIdx.x * 4 + wid;
  const float* src = F + (size_t)row * DD + lane * 8;
  float4 a = *(const float4*)src;
  float4 b = *(const float4*)(src + 4);
  float v[8] = {a.x, a.y, a.z, a.w, b.x, b.y, b.z, b.w};
  const float* kp = kb + lane * 8;
  float4 ka = *(const float4*)kp;
  float4 kc = *(const float4*)(kp + 4);
  float kw[8] = {ka.x, ka.y, ka.z, ka.w, kc.x, kc.y, kc.z, kc.w};
  u16 h[8];
  float s = 0.f, d = 0.f;
#pragma unroll
  for (int j = 0; j < 8; ++j) {
    h[j] = f2bf(v[j]);
    float f = bf2f(h[j]);
    s += f * f;
    d += f * kw[j];
  }
  u32 pk[4];
#pragma unroll
  for (int j = 0; j < 4; ++j) pk[j] = (u32)h[2 * j] | ((u32)h[2 * j + 1] << 16);
  *(uint4*)(Fb + (size_t)row * DD + lane * 8) = make_uint4(pk[0], pk[1], pk[2], pk[3]);
#pragma unroll
  for (int dd = 1; dd < 64; dd <<= 1) { s += __shfl_xor(s, dd); d += __shfl_xor(d, dd); }
  if (lane == 0) nv[row] = make_float2(s, d);
}

// ---- MT[m][k] = (Wq^T Wk)^T[m][k] / sqrt(d) = sum_a WkT[m,a]*WqT[k,a] -------
__global__ __launch_bounds__(256) void mt_kernel(const u16* __restrict__ WkT,
                                                 const u16* __restrict__ WqT,
                                                 u16* __restrict__ MT) {
  int lane = threadIdx.x & 63, wm = threadIdx.x >> 6;
  int l15 = lane & 15, lg = lane >> 4;
  int rowA = blockIdx.x * 64 + wm * 16 + l15;
  int rowC0 = blockIdx.x * 64 + wm * 16 + lg * 4;
  int colbase = blockIdx.y * 64;
  f32x4 z = {0.f, 0.f, 0.f, 0.f};
  f32x4 acc[4] = {z, z, z, z};
#pragma unroll
  for (int kk = 0; kk < 16; ++kk) {
    bf16x8 aF = *(const bf16x8*)(WkT + (size_t)rowA * DD + kk * 32 + lg * 8);
#pragma unroll
    for (int nf = 0; nf < 4; ++nf) {
      bf16x8 bW = *(const bf16x8*)(WqT + (size_t)(colbase + nf * 16 + l15) * DD + kk * 32 + lg * 8);
      acc[nf] = mfma_bf16(aF, bW, acc[nf]);
    }
  }
  const float isd = 0.04419417382415922f;
#pragma unroll
  for (int nf = 0; nf < 4; ++nf) {
    int col = colbase + nf * 16 + l15;
#pragma unroll
    for (int r = 0; r < 4; ++r)
      MT[(size_t)(rowC0 + r) * DD + col] = f2bf(acc[nf][r] * isd);
  }
}

// ---- G = Fb @ MT^T (mat 0) ; V = Fb @ Wv^T + bv -> Vt (mat 1) ---------------
__global__ __launch_bounds__(256) void gv_kernel(
    const u16* __restrict__ Fb, const u16* __restrict__ MT, const u16* __restrict__ Wvb,
    const float* __restrict__ bv, u16* __restrict__ G, u16* __restrict__ Vt) {
  int mat = blockIdx.z;
  const u16* W = (mat == 0) ? MT : Wvb;
  int lane = threadIdx.x & 63, wm = threadIdx.x >> 6;
  int l15 = lane & 15, lg = lane >> 4;
  int rowA = blockIdx.x * 64 + wm * 16 + l15;
  int rowC0 = blockIdx.x * 64 + wm * 16 + lg * 4;
  int colbase = blockIdx.y * 64;
  f32x4 z = {0.f, 0.f, 0.f, 0.f};
  f32x4 acc[4] = {z, z, z, z};
#pragma unroll
  for (int kk = 0; kk < 16; ++kk) {
    bf16x8 aF = *(const bf16x8*)(Fb + (size_t)rowA * DD + kk * 32 + lg * 8);
#pragma unroll
    for (int nf = 0; nf < 4; ++nf) {
      bf16x8 bW = *(const bf16x8*)(W + (size_t)(colbase + nf * 16 + l15) * DD + kk * 32 + lg * 8);
      acc[nf] = mfma_bf16(aF, bW, acc[nf]);
    }
  }
#pragma unroll
  for (int nf = 0; nf < 4; ++nf) {
    int col = colbase + nf * 16 + l15;
    if (mat == 1) {
      float bb = bv[col];
      ushort4 vv = make_ushort4(f2bf(acc[nf][0] + bb), f2bf(acc[nf][1] + bb),
                                f2bf(acc[nf][2] + bb), f2bf(acc[nf][3] + bb));
      *(ushort4*)(Vt + (size_t)col * PP + rowC0) = vv;
    } else {
#pragma unroll
      for (int r = 0; r < 4; ++r)
        G[(size_t)(rowC0 + r) * DD + col] = f2bf(acc[nf][r]);
    }
  }
}

// ---- fused flash attention + dist -------------------------------------------
// 256 blocks (BM=32 rows), 512 threads = 8 waves.
// S-phase: waves = wm(2) x wn(4), keys kl = wn*16+l15.
// PV-phase: each wave owns cols [wid*64, wid*64+64) and computes BOTH 16-row
//           groups (each bV load feeds 2 MFMAs -> Vt L2 traffic halved).
// amdgpu_waves_per_eu(2,2): VGPR budget 256 so gf[16]/ff[16]/o[8] stay resident
// (round-1 showed capping at 128/64 VGPR causes an L2/scratch reload storm).
__global__ __launch_bounds__(512)
__attribute__((amdgpu_waves_per_eu(2, 2))) void fused_kernel(
    const u16* __restrict__ G, const u16* __restrict__ Fb, const u16* __restrict__ Vt,
    const float2* __restrict__ nv, const float* __restrict__ lamp,
    float* __restrict__ out) {
  float* Fout = out;
  float* Dist = out + (size_t)PP * DD;
  const float lam = lamp[0];
  int lane = threadIdx.x & 63, wid = threadIdx.x >> 6;
  int wm = wid >> 2, wn = wid & 3;
  int l15 = lane & 15, lg = lane >> 4;
  int rowA = blockIdx.x * 32 + wm * 16 + l15;
  int rowC0 = blockIdx.x * 32 + wm * 16 + lg * 4;

  __shared__ u16 Ftile[2][64][DD];   // 128 KiB double-buffered key tile
  __shared__ u16 P_lds[32][72];
  __shared__ float redmax[8][16];
  __shared__ float redsum[8][16];

  // resident A-fragments: G (scores) and F (Gram) rows — 128 VGPRs, loop-invariant
  bf16x8 gf[16], ff[16];
#pragma unroll
  for (int c = 0; c < 16; ++c) {
    gf[c] = *(const bf16x8*)(G + (size_t)rowA * DD + c * 32 + lg * 8);
    ff[c] = *(const bf16x8*)(Fb + (size_t)rowA * DD + c * 32 + lg * 8);
  }
  float ni[4];
#pragma unroll
  for (int r = 0; r < 4; ++r) ni[r] = nv[rowC0 + r].x;
  // running softmax state for BOTH row groups (PV rescale needs both)
  float m_run[2][4], l_run[2][4];
#pragma unroll
  for (int g = 0; g < 2; ++g)
#pragma unroll
    for (int r = 0; r < 4; ++r) { m_run[g][r] = -1e30f; l_run[g][r] = 0.f; }
  f32x4 z = {0.f, 0.f, 0.f, 0.f};
  f32x4 o[8] = {z, z, z, z, z, z, z, z};   // [g*4+nt]: g=row group, nt=col tile

  int kl = wn * 16 + l15;      // B-side key_local (S-phase)
  int swz = kl & 7;
  int col0 = wid * 64;         // PV column slice owned by this wave

  // prologue: stage tile 0
#pragma unroll
  for (int t = 0; t < 8; ++t) {
    int row = wid * 8 + t;
    gload_lds16(Fb + (size_t)row * DD + ((lane ^ (row & 7)) * 8), &Ftile[0][row][0]);
  }
  __syncthreads();

#pragma unroll 1
  for (int jt = 0; jt < PP / 64; ++jt) {
    int key0 = jt * 64;
    int cur = jt & 1;
    // stage next tile (in flight across S-phase; drained at sync1)
    if (jt + 1 < PP / 64) {
      int nb = cur ^ 1;
#pragma unroll
      for (int t = 0; t < 8; ++t) {
        int row = wid * 8 + t;
        gload_lds16(Fb + (size_t)(key0 + 64 + row) * DD + ((lane ^ (row & 7)) * 8),
                    &Ftile[nb][row][0]);
      }
    }
    // S phase: scores (G.F^T) and Gram (F.F^T) off shared B-frags
    const u16* ft = &Ftile[cur][0][0];
    f32x4 sqk = z, sff = z;
#pragma unroll
    for (int kk = 0; kk < 16; ++kk) {
      bf16x8 bF = *(const bf16x8*)(ft + (size_t)kl * DD + (((kk * 4 + lg) ^ swz) * 8));
      sqk = mfma_bf16(gf[kk], bF, sqk);
      sff = mfma_bf16(ff[kk], bF, sff);
    }
    int colB = key0 + kl;
    float2 nvj = nv[colB];
    float pv[4], tmax[4];
#pragma unroll
    for (int r = 0; r < 4; ++r) {
      float sq = ni[r] + nvj.x - 2.0f * sff[r];
      sq = fmaxf(sq, 0.f);
      float dist = sqrtf(sq);
      Dist[(size_t)(rowC0 + r) * PP + colB] = dist;
      float s = sqk[r] + nvj.y - lam * dist;
      pv[r] = s;
      tmax[r] = s;
    }
#pragma unroll
    for (int d = 1; d < 16; d <<= 1) {
#pragma unroll
      for (int r = 0; r < 4; ++r) tmax[r] = fmaxf(tmax[r], __shfl_xor(tmax[r], d));
    }
    if (l15 == 0) {
#pragma unroll
      for (int r = 0; r < 4; ++r) redmax[wid][lg * 4 + r] = tmax[r];
    }
    __syncthreads();  // sync1 (also drains the stage loads)
    // all waves compute new max + alpha for BOTH row groups
    float mnew[2][4], alpha[2][4];
#pragma unroll
    for (int g = 0; g < 2; ++g) {
#pragma unroll
      for (int r = 0; r < 4; ++r) {
        float mt = m_run[g][r];
#pragma unroll
        for (int ow = 0; ow < 4; ++ow) mt = fmaxf(mt, redmax[g * 4 + ow][lg * 4 + r]);
        mnew[g][r] = mt;
        alpha[g][r] = __expf(m_run[g][r] - mt);
      }
    }
    float tsum[4];
#pragma unroll
    for (int r = 0; r < 4; ++r) {
      float mo = (wm == 0) ? mnew[0][r] : mnew[1][r];
      pv[r] = __expf(pv[r] - mo);
      tsum[r] = pv[r];
    }
#pragma unroll
    for (int d = 1; d < 16; d <<= 1) {
#pragma unroll
      for (int r = 0; r < 4; ++r) tsum[r] += __shfl_xor(tsum[r], d);
    }
#pragma unroll
    for (int r = 0; r < 4; ++r)
      P_lds[wm * 16 + lg * 4 + r][wn * 16 + l15] = f2bf(pv[r]);
    if (l15 == 0) {
#pragma unroll
      for (int r = 0; r < 4; ++r) redsum[wid][lg * 4 + r] = tsum[r];
    }
    __syncthreads();  // sync2
#pragma unroll
    for (int g = 0; g < 2; ++g) {
#pragma unroll
      for (int r = 0; r < 4; ++r) {
        float s4 = 0.f;
#pragma unroll
        for (int ow = 0; ow < 4; ++ow) s4 += redsum[g * 4 + ow][lg * 4 + r];
        l_run[g][r] = l_run[g][r] * alpha[g][r] + s4;
        m_run[g][r] = mnew[g][r];
      }
    }
#pragma unroll
    for (int g = 0; g < 2; ++g) {
#pragma unroll
      for (int nt = 0; nt < 4; ++nt) {
#pragma unroll
        for (int r = 0; r < 4; ++r) o[g * 4 + nt][r] *= alpha[g][r];
      }
    }
    // PV: wave's 64-col slice, both row groups share each bV load
#pragma unroll
    for (int kc = 0; kc < 2; ++kc) {
      bf16x8 aP0 = *(const bf16x8*)(&P_lds[l15][kc * 32 + lg * 8]);
      bf16x8 aP1 = *(const bf16x8*)(&P_lds[16 + l15][kc * 32 + lg * 8]);
#pragma unroll
      for (int nt = 0; nt < 4; ++nt) {
        int n = col0 + nt * 16 + l15;
        bf16x8 bV = *(const bf16x8*)(Vt + (size_t)n * PP + key0 + kc * 32 + lg * 8);
        o[nt] = mfma_bf16(aP0, bV, o[nt]);
        o[4 + nt] = mfma_bf16(aP1, bV, o[4 + nt]);
      }
    }
  }
  float inv[2][4];
#pragma unroll
  for (int g = 0; g < 2; ++g)
#pragma unroll
    for (int r = 0; r < 4; ++r) inv[g][r] = 1.0f / l_run[g][r];
#pragma unroll
  for (int g = 0; g < 2; ++g) {
#pragma unroll
    for (int nt = 0; nt < 4; ++nt) {
#pragma unroll
      for (int r = 0; r < 4; ++r)
        Fout[(size_t)(blockIdx.x * 32 + g * 16 + lg * 4 + r) * DD + col0 + nt * 16 + l15] =
            o[g * 4 + nt][r] * inv[g][r];
    }
  }
}

extern "C" void kernel_launch(void* const* d_in, const int* in_sizes, int n_in,
                              void* d_out, int out_size, void* d_ws, size_t ws_size,
                              hipStream_t stream) {
  const float* F   = (const float*)d_in[0];
  const float* Wq  = (const float*)d_in[1];
  const float* bq  = (const float*)d_in[2];
  const float* Wk  = (const float*)d_in[3];
  const float* bk  = (const float*)d_in[4];
  const float* Wv  = (const float*)d_in[5];
  const float* bv  = (const float*)d_in[6];
  const float* lam = (const float*)d_in[7];
  float* out = (float*)d_out;
  (void)bk;

  u16* ws  = (u16*)d_ws;
  u16* Fb  = ws;                               // [PP][DD]
  u16* G   = Fb + (size_t)PP * DD;             // [PP][DD]
  u16* Vt  = G + (size_t)PP * DD;              // [DD][PP]
  u16* WqT = Vt + (size_t)PP * DD;             // [DD][DD]
  u16* WkT = WqT + (size_t)DD * DD;
  u16* Wvb = WkT + (size_t)DD * DD;
  u16* MT  = Wvb + (size_t)DD * DD;
  float2* nv = (float2*)(MT + (size_t)DD * DD);  // [PP]
  float* kb  = (float*)(nv + PP);                // [DD]

  prep_wt_kernel<<<1024, 256, 0, stream>>>(Wq, Wk, Wv, WqT, WkT, Wvb);
  kb_kernel<<<1, 512, 0, stream>>>(Wk, bq, kb);
  prep_f_kernel<<<PP / 4, 256, 0, stream>>>(F, kb, Fb, nv);
  mt_kernel<<<dim3(8, 8), 256, 0, stream>>>(WkT, WqT, MT);
  gv_kernel<<<dim3(PP / 64, DD / 64, 2), 256, 0, stream>>>(Fb, MT, Wvb, bv, G, Vt);
  fused_kernel<<<PP / 32, 512, 0, stream>>>(G, Fb, Vt, nv, lam, out);
}